// Round 7
// baseline (1123.491 us; speedup 1.0000x reference)
//
#include <hip/hip_runtime.h>
#include <hip/hip_cooperative_groups.h>
#include <cstdint>
#include <cstddef>

#define NV 200000
#define NT 800000
#define ROWS 64
#define NBLK 3125   // 3125*64 = 200000 exactly

#define CG 512        // coop grid blocks
#define CT 256        // coop block threads
#define CTH (CG*CT)   // 131072 coop threads
#define TPT 7         // tets per thread in P1 (131072*7 >= 800000)
#define NSEG 782      // ceil(NV/256)

typedef unsigned int u32;
typedef unsigned long long u64;
typedef unsigned short ushort_t;

typedef __attribute__((ext_vector_type(8))) _Float16 half8;
typedef __attribute__((ext_vector_type(4))) float f32x4;
#define MFMA16F __builtin_amdgcn_mfma_f32_16x16x32_f16

namespace cg = cooperative_groups;

// ---------------- marching-tets tables ----------------
__constant__ int c_tri[16][6] = {
  {-1,-1,-1,-1,-1,-1},{1,0,2,-1,-1,-1},{4,0,3,-1,-1,-1},{1,4,2,1,3,4},
  {3,1,5,-1,-1,-1},{2,3,0,2,5,3},{1,4,0,1,5,4},{4,2,5,-1,-1,-1},
  {4,5,2,-1,-1,-1},{4,1,0,4,5,1},{3,2,0,3,5,2},{1,3,5,-1,-1,-1},
  {4,1,2,4,3,1},{3,0,4,-1,-1,-1},{2,0,1,-1,-1,-1},{-1,-1,-1,-1,-1,-1}};
__constant__ int c_ntri[16] = {0,1,1,2,1,2,2,1,1,2,2,1,2,1,1,0};
__constant__ int c_be[12] = {0,1,0,2,0,3,1,2,1,3,2,3};

// ---------------- fp16 Dekker 2-way split: x ~= h + m*2^-11, m kept normal ----------------
__device__ __forceinline__ void split2(float x, _Float16& h, _Float16& m){
  h = (_Float16)x;
  const float r = x - (float)h;
  m = (_Float16)(r * 2048.0f);
}

// ---------------- weight split prep: fp32 W -> 2 fp16 planes, chunk-blocked [c][n][32k] ----------------
__global__ void split_weights(const float* __restrict__ w0, const float* __restrict__ w1,
                              const float* __restrict__ w2, const float* __restrict__ w3,
                              _Float16* __restrict__ wp)
{
  const int idx = blockIdx.x*256 + threadIdx.x;   // 0..204799
  int base, k, n, psz;
  float val;
  if (idx < 8192){                                  // layer0: K=27 padded to 32
    base = 0; psz = 8192; k = idx >> 8; n = idx & 255;
    val = (k < 27) ? w0[k*256 + n] : 0.f;
  } else {
    int r = idx - 8192;
    const int l = r >> 16;                          // 0..2 -> layers 1..3
    r &= 65535;
    k = r >> 8; n = r & 255; psz = 65536;
    base = 16384 + l*131072;
    const float* w = (l==0) ? w1 : (l==1) ? w2 : w3;
    val = w[k*256 + n];
  }
  _Float16 h, m; split2(val, h, m);
  const int c = k >> 5, kk = k & 31;
  const int off = (c*256 + n)*32 + kk;
  wp[base + off] = h;
  wp[base + psz + off] = m;
}

// ---------------- MFMA MLP (unchanged from round 4: ~255 us, 2 blocks/CU) ----------------
template<int NC, bool LAST>
__device__ __forceinline__ void layer_run(
    const _Float16* __restrict__ Wl, const float* __restrict__ Bv,
    const float* __restrict__ wfv,
    _Float16 (*Af)[ROWS][264], float (*part)[8],
    int lane, int wv)
{
  const int l15 = lane & 15, q = lane >> 4;
  const int col0 = wv * 32;
  f32x4 g0[4][2], g1[4][2];
#pragma unroll
  for (int i=0;i<4;i++)
#pragma unroll
    for (int j=0;j<2;j++){ g0[i][j] = (f32x4){0.f,0.f,0.f,0.f}; g1[i][j] = (f32x4){0.f,0.f,0.f,0.f}; }

  const _Float16* bp = Wl + (u32)((col0 + l15)*32 + q*8);
  half8 bA[2][2], bB[2][2];

  auto loadB = [&](int c, half8 (*dst)[2]){
#pragma unroll
    for (int p=0;p<2;p++)
#pragma unroll
      for (int nt=0;nt<2;nt++)
        dst[p][nt] = *(const half8*)(bp + (p*NC + c)*8192 + nt*512);
  };
  auto compute = [&](int c, const half8 (*bb)[2]){
#pragma unroll
    for (int mt=0;mt<4;mt++){
      const _Float16* ap = &Af[0][mt*16 + l15][c*32 + q*8];
      const half8 ah = *(const half8*)(ap);
      const half8 am = *(const half8*)(ap + ROWS*264);
#pragma unroll
      for (int nt=0;nt<2;nt++){
        g0[mt][nt] = MFMA16F(ah, bb[0][nt], g0[mt][nt], 0,0,0);   // h*h
        g1[mt][nt] = MFMA16F(ah, bb[1][nt], g1[mt][nt], 0,0,0);   // h*m'
        g1[mt][nt] = MFMA16F(am, bb[0][nt], g1[mt][nt], 0,0,0);   // m'*h
      }
    }
  };

  loadB(0, bA);
  if (NC == 1){
    compute(0, bA);
  } else {
#pragma unroll 1
    for (int ch=0; ch<NC/2; ch++){
      const int c0 = 2*ch;
      loadB(c0+1, bB);
      compute(c0, bA);
      if (c0+2 < NC) loadB(c0+2, bA);
      compute(c0+1, bB);
    }
  }
  __syncthreads();

  const float S = 4.8828125e-4f;         // 2^-11
  if (!LAST){
#pragma unroll
    for (int nt=0;nt<2;nt++){
      const int col = col0 + nt*16 + l15;
      const float bias = Bv[col];
#pragma unroll
      for (int mt=0;mt<4;mt++)
#pragma unroll
        for (int reg=0;reg<4;reg++){
          const int row = mt*16 + q*4 + reg;
          const float v = fmaxf(g0[mt][nt][reg] + S*g1[mt][nt][reg] + bias, 0.f);
          _Float16 h,m; split2(v,h,m);
          Af[0][row][col] = h; Af[1][row][col] = m;
        }
    }
  } else {
    float pr[4][4];
#pragma unroll
    for (int mt=0;mt<4;mt++)
#pragma unroll
      for (int reg=0;reg<4;reg++) pr[mt][reg] = 0.f;
#pragma unroll
    for (int nt=0;nt<2;nt++){
      const int col = col0 + nt*16 + l15;
      const float bias = Bv[col];
      const float w = wfv[col];
#pragma unroll
      for (int mt=0;mt<4;mt++)
#pragma unroll
        for (int reg=0;reg<4;reg++)
          pr[mt][reg] += fmaxf(g0[mt][nt][reg] + S*g1[mt][nt][reg] + bias, 0.f) * w;
    }
#pragma unroll
    for (int s=1;s<16;s<<=1)
#pragma unroll
      for (int mt=0;mt<4;mt++)
#pragma unroll
        for (int reg=0;reg<4;reg++)
          pr[mt][reg] += __shfl_xor(pr[mt][reg], s, 64);
    if (l15 == 0){
#pragma unroll
      for (int mt=0;mt<4;mt++)
#pragma unroll
        for (int reg=0;reg<4;reg++)
          part[mt*16 + q*4 + reg][wv] = pr[mt][reg];
    }
  }
  __syncthreads();
}

__global__ __launch_bounds__(512,4) void mlp_mfma(
    const float* __restrict__ pos, const _Float16* __restrict__ wp,
    const float* __restrict__ b0, const float* __restrict__ b1,
    const float* __restrict__ b2, const float* __restrict__ b3,
    const float* __restrict__ wf, const float* __restrict__ bf,
    float* __restrict__ sdf)
{
  __shared__ _Float16 Af[2][ROWS][264];
  __shared__ float part[ROWS][8];
  const int tid = threadIdx.x;
  const int lane = tid & 63, wv = tid >> 6;
  const int row0 = blockIdx.x * ROWS;

#pragma unroll
  for (int it=0; it<4; it++){
    const int idx = it*512 + tid;
    const int r = idx & 63, f = idx >> 6;
    float val = 0.f;
    if (f < 3){
      val = pos[(row0 + r)*3 + f];
    } else if (f < 27){
      const int g = (f-3)/6, rem = (f-3)%6;
      const int d = rem % 3;
      const float x = pos[(row0 + r)*3 + d];
      const float fr = (float)(1 << g) * 3.14159265358979323846f;
      val = (rem < 3) ? sinf(fr*x) : cosf(fr*x);
    }
    _Float16 h,m; split2(val,h,m);
    Af[0][r][f] = h; Af[1][r][f] = m;
  }
  __syncthreads();

  layer_run<1,false>(wp + 0,      b0, nullptr, Af, part, lane, wv);
  layer_run<8,false>(wp + 16384,  b1, nullptr, Af, part, lane, wv);
  layer_run<8,false>(wp + 147456, b2, nullptr, Af, part, lane, wv);
  layer_run<8,true >(wp + 278528, b3, wf,      Af, part, lane, wv);

  if (tid < ROWS){
    float s = 0.f;
#pragma unroll
    for (int w=0; w<8; w++) s += part[tid][w];
    sdf[row0 + tid] = s + bf[0];
  }
}

// ================= fused marching-tets: one cooperative kernel =================
// Exact two-pass buckets (count -> scan -> fill): robust to arbitrary bucket skew.
struct TetArgs {
  const int* tet; const float* pos; const float* sdf;
  unsigned char* codes;
  u32* cnt;      // P1: counts; P2: in-place inclusive 256-segment scan (frozen after)
  u32* ucnt;     // P0: zeroed; P4: fill cursor; P5: unique count per lo
  u32* ucnt_ex;  // P6: exclusive within 256-segment
  u32* ttot;     // P1: packed (n1,n2) per thread; P2: in-place exclusive within block
  u32* btot;     // per-block packed totals
  u64* btot_ex;  // per-block exclusive (n1 lo32, n2 hi32)
  u32* bseg; u32* bseg_ex;  // per-256-segment edge totals / exclusive
  u32* ubt; u32* ubt_ex;    // per-256-segment unique totals / exclusive
  u32* meta; u32* tscan;
  int* ehi; int ecap;
  float* out; int out_size;
};

__device__ __forceinline__ u32 bscan_u32(u32 v, u32* sh, int tid){
  sh[tid]=v; __syncthreads();
#pragma unroll
  for (int s=1;s<256;s<<=1){
    const u32 y = (tid>=s) ? sh[tid-s] : 0u;
    __syncthreads();
    sh[tid] += y;
    __syncthreads();
  }
  return sh[tid];
}
__device__ __forceinline__ u64 bscan_u64(u64 v, u64* sh, int tid){
  sh[tid]=v; __syncthreads();
#pragma unroll
  for (int s=1;s<256;s<<=1){
    const u64 y = (tid>=s) ? sh[tid-s] : 0ull;
    __syncthreads();
    sh[tid] += y;
    __syncthreads();
  }
  return sh[tid];
}

__global__ __launch_bounds__(CT,4) void coop_tets(TetArgs a)
{
  cg::grid_group grid = cg::this_grid();
  __shared__ u32 sh[CT];
  __shared__ u64 sh64[CT];
  const int tid = threadIdx.x;
  const u32 g = blockIdx.x*CT + tid;

  // ---- P0: zero counters + fill cursors ----
  for (u32 i = g; i < NV; i += CTH){ a.cnt[i] = 0u; a.ucnt[i] = 0u; }
  grid.sync();

  // ---- P1: codes, thread-local stable (n1,n2) prefix, bucket COUNT ----
  {
    int n1=0, n2=0;
    const int tbeg = (int)g * TPT;
#pragma unroll 1
    for (int i=0;i<TPT;i++){
      const int t = tbeg + i;
      int nt = 0;
      if (t < NT){
        a.tscan[t] = (u32)n1 | ((u32)n2<<16);
        const int4 v = *(const int4*)(&a.tet[4*t]);
        const int o0 = a.sdf[v.x] > 0.f;
        const int o1 = a.sdf[v.y] > 0.f;
        const int o2 = a.sdf[v.z] > 0.f;
        const int o3 = a.sdf[v.w] > 0.f;
        const int code = o0 | (o1<<1) | (o2<<2) | (o3<<3);
        a.codes[t] = (unsigned char)code;
        nt = c_ntri[code];
        if (nt > 0){
          const int vv[4] = {v.x, v.y, v.z, v.w};
          const int oc[4] = {o0,o1,o2,o3};
#pragma unroll
          for (int e=0;e<6;e++){
            const int ia = c_be[2*e], ib = c_be[2*e+1];
            if (oc[ia] != oc[ib]){
              const int p = vv[ia], q = vv[ib];
              const int lo = p<q ? p : q;
              atomicAdd(&a.cnt[lo], 1u);
            }
          }
        }
      }
      n1 += (nt==1);
      n2 += (nt==2);
    }
    a.ttot[g] = (u32)n1 | ((u32)n2<<16);
  }
  grid.sync();

  // ---- P2: ttot block-scan in place (-> exclusive); cnt 256-seg scan in place (-> inclusive) ----
  {
    const u32 v = a.ttot[g];
    const u32 incl = bscan_u32(v, sh, tid);
    a.ttot[g] = incl - v;
    if (tid == CT-1) a.btot[blockIdx.x] = incl;
    __syncthreads();
  }
  for (u32 s = blockIdx.x; s < NSEG; s += CG){
    const u32 idx = s*256 + tid;
    const u32 v = (idx < NV) ? a.cnt[idx] : 0u;
    const u32 incl = bscan_u32(v, sh, tid);
    if (idx < NV) a.cnt[idx] = incl;          // inclusive within its 256-segment
    if (tid == CT-1) a.bseg[s] = incl;
    __syncthreads();
  }
  grid.sync();

  // ---- P3: top-level scans: bseg (block 0), btot (block CG-1) ----
  if (blockIdx.x == 0){
    u32 v4[4]; u32 tot = 0;
#pragma unroll
    for (int i=0;i<4;i++){
      const u32 idx = tid*4 + i;
      v4[i] = (idx < NSEG) ? a.bseg[idx] : 0u;
      tot += v4[i];
    }
    const u32 incl = bscan_u32(tot, sh, tid);
    u32 run = incl - tot;
#pragma unroll
    for (int i=0;i<4;i++){
      const u32 idx = tid*4 + i;
      if (idx < NSEG) a.bseg_ex[idx] = run;
      run += v4[i];
    }
  }
  if (blockIdx.x == CG-1){
    const u32 p0 = a.btot[2*tid], p1 = a.btot[2*tid+1];
    const u64 v0 = (u64)(p0 & 0xffffu) | ((u64)(p0 >> 16) << 32);
    const u64 v1 = (u64)(p1 & 0xffffu) | ((u64)(p1 >> 16) << 32);
    const u64 pair = v0 + v1;
    const u64 incl = bscan_u64(pair, sh64, tid);
    a.btot_ex[2*tid]   = incl - pair;
    a.btot_ex[2*tid+1] = incl - pair + v0;
    if (tid == CT-1){ a.meta[0] = (u32)(incl & 0xffffffffull); a.meta[1] = (u32)(incl >> 32); }
  }
  grid.sync();

  // ---- P4: FILL pass (cursor = ucnt, zeroed in P0) ----
  for (u32 t = g; t < NT; t += CTH){
    const int code = a.codes[t];
    if (c_ntri[code] == 0) continue;
    const int4 v = *(const int4*)(&a.tet[4*t]);
    const int vv[4] = {v.x, v.y, v.z, v.w};
    const int oc[4] = {code&1,(code>>1)&1,(code>>2)&1,(code>>3)&1};
#pragma unroll
    for (int e=0;e<6;e++){
      const int ia = c_be[2*e], ib = c_be[2*e+1];
      if (oc[ia] != oc[ib]){
        const int p = vv[ia], q = vv[ib];
        const int lo = p<q ? p : q, hi = p<q ? q : p;
        const u32 excl = (lo & 255) ? a.cnt[lo-1] : 0u;
        const u32 off = a.bseg_ex[lo>>8] + excl;
        const u32 slot = atomicAdd(&a.ucnt[lo], 1u);
        const u32 idx = off + slot;
        if (idx < (u32)a.ecap) a.ehi[idx] = hi;
      }
    }
  }
  grid.sync();

  // ---- P5: per-bucket sort + dedup; ucnt <- unique count ----
  for (u32 lo = g; lo < NV; lo += CTH){
    const u32 inclv = a.cnt[lo];
    const u32 exclv = (lo & 255) ? a.cnt[lo-1] : 0u;
    int n = (int)(inclv - exclv);
    const u32 off = a.bseg_ex[lo>>8] + exclv;
    long long rem = (long long)a.ecap - (long long)off;
    if (rem < 0) rem = 0;
    if ((long long)n > rem) n = (int)rem;
    int* b = a.ehi + off;
    for (int i=1;i<n;i++){
      const int key = b[i];
      int j=i-1;
      while (j>=0 && b[j] > key){ b[j+1]=b[j]; j--; }
      b[j+1]=key;
    }
    int u=0, prev=-1;
    for (int i=0;i<n;i++){
      const int x = b[i];
      if (x != prev){ b[u]=x; u++; prev=x; }
    }
    a.ucnt[lo] = (u32)u;
  }
  grid.sync();

  // ---- P6: ucnt 256-segment scans -> ucnt_ex, ubt ----
  for (u32 s = blockIdx.x; s < NSEG; s += CG){
    const u32 idx = s*256 + tid;
    const u32 v = (idx < NV) ? a.ucnt[idx] : 0u;
    const u32 incl = bscan_u32(v, sh, tid);
    if (idx < NV) a.ucnt_ex[idx] = incl - v;
    if (tid == CT-1) a.ubt[s] = incl;
    __syncthreads();
  }
  grid.sync();

  // ---- P7: scan ubt (block 0) -> ubt_ex, meta[3] = M ----
  if (blockIdx.x == 0){
    u32 v4[4]; u32 tot = 0;
#pragma unroll
    for (int i=0;i<4;i++){
      const u32 idx = tid*4 + i;
      v4[i] = (idx < NSEG) ? a.ubt[idx] : 0u;
      tot += v4[i];
    }
    const u32 incl = bscan_u32(tot, sh, tid);
    u32 run = incl - tot;
#pragma unroll
    for (int i=0;i<4;i++){
      const u32 idx = tid*4 + i;
      if (idx < NSEG) a.ubt_ex[idx] = run;
      run += v4[i];
    }
    if (tid == CT-1) a.meta[3] = incl;
  }
  grid.sync();

  // ---- P8: emit verts + faces ----
  for (u32 lo = g; lo < NV; lo += CTH){
    const int u = (int)a.ucnt[lo];
    if (u == 0) continue;
    const u32 exclv = (lo & 255) ? a.cnt[lo-1] : 0u;
    const int* b = a.ehi + (a.bseg_ex[lo>>8] + exclv);
    const u32 idbase = a.ubt_ex[lo>>8] + a.ucnt_ex[lo];
    const float s0 = a.sdf[lo];
    const float p0x = a.pos[3*lo], p0y = a.pos[3*lo+1], p0z = a.pos[3*lo+2];
    for (int j=0;j<u;j++){
      const int hi = b[j];
      const float s1 = a.sdf[hi];
      const float d = s0 - s1;
      const float vx = (p0x*(-s1) + a.pos[3*hi  ]*s0) / d;
      const float vy = (p0y*(-s1) + a.pos[3*hi+1]*s0) / d;
      const float vz = (p0z*(-s1) + a.pos[3*hi+2]*s0) / d;
      const long long w = 3ll*(long long)(idbase + (u32)j);
      if (w + 3 <= (long long)a.out_size){
        a.out[w] = vx; a.out[w+1] = vy; a.out[w+2] = vz;
      }
    }
  }
  const u32 N1 = a.meta[0];
  const u32 M  = a.meta[3];
  for (u32 t = g; t < NT; t += CTH){
    const int code = a.codes[t];
    const int nt = c_ntri[code];
    if (nt == 0) continue;
    const u32 og = t / TPT;                 // owning P1 thread
    const u64 tb = a.btot_ex[og >> 8];      // owning block's exclusive totals
    const u32 te = a.ttot[og];              // thread's exclusive within block
    const u32 ts = a.tscan[t];
    const u32 n1e = (u32)(tb & 0xffffffffull) + (te & 0xffffu) + (ts & 0xffffu);
    const u32 n2e = (u32)(tb >> 32) + (te >> 16) + (ts >> 16);
    const u32 fb = (nt==1) ? n1e : (N1 + 2u*n2e);
    const int4 v = *(const int4*)(&a.tet[4*t]);
    const int vv[4] = {v.x, v.y, v.z, v.w};
    for (int r=0;r<nt;r++){
      for (int k=0;k<3;k++){
        const int e = c_tri[code][3*r+k];
        const int ia = c_be[2*e], ib = c_be[2*e+1];
        const int p = vv[ia], q = vv[ib];
        const int lo = p<q ? p : q, hi = p<q ? q : p;
        const u32 exclv = (lo & 255) ? a.cnt[lo-1] : 0u;
        const int* b = a.ehi + (a.bseg_ex[lo>>8] + exclv);
        const int u = (int)a.ucnt[lo];
        int id = -1;
        for (int j=0;j<u;j++){
          if (b[j] == hi){ id = (int)(a.ubt_ex[lo>>8] + a.ucnt_ex[lo]) + j; break; }
        }
        const long long w = 3ll*(long long)M + 3ll*(long long)(fb + (u32)r) + k;
        if (w < (long long)a.out_size && id >= 0) a.out[w] = (float)id;
      }
    }
  }
}

// ---------------- launch ----------------
extern "C" void kernel_launch(void* const* d_in, const int* in_sizes, int n_in,
                              void* d_out, int out_size, void* d_ws, size_t ws_size,
                              hipStream_t stream)
{
  (void)in_sizes; (void)n_in;
  const float* pos = (const float*)d_in[0];
  const int*   tet = (const int*)d_in[1];
  const float* w0 = (const float*)d_in[2];
  const float* b0 = (const float*)d_in[3];
  const float* w1 = (const float*)d_in[4];
  const float* b1 = (const float*)d_in[5];
  const float* w2 = (const float*)d_in[6];
  const float* b2 = (const float*)d_in[7];
  const float* w3 = (const float*)d_in[8];
  const float* b3 = (const float*)d_in[9];
  const float* wf = (const float*)d_in[10];
  const float* bf = (const float*)d_in[11];
  float* out = (float*)d_out;
  char* ws = (char*)d_ws;

  float*         sdf   = (float*)(ws + 0);               // 800000 B
  unsigned char* codes = (unsigned char*)(ws + 800000);  // 800000 B
  u32* cnt     = (u32*)(ws + 1600000);                   // 800000 B
  u32* ucnt    = (u32*)(ws + 2400000);                   // 800000 B
  u32* ucnt_ex = (u32*)(ws + 3200000);                   // 800000 B
  u32* ttot    = (u32*)(ws + 4000000);                   // 524288 B
  u32* btot    = (u32*)(ws + 4524288);                   // 2048 B
  u64* btot_ex = (u64*)(ws + 4526336);                   // 4096 B
  u32* bseg    = (u32*)(ws + 4530432);                   // 4096 B
  u32* bseg_ex = (u32*)(ws + 4534528);                   // 4096 B
  u32* ubt     = (u32*)(ws + 4538624);                   // 4096 B
  u32* ubt_ex  = (u32*)(ws + 4542720);                   // 4096 B
  u32* meta    = (u32*)(ws + 4546816);                   // 64 B
  u32* tscan   = (u32*)(ws + 4546880);                   // 3200000 B
  _Float16* wp = (_Float16*)(ws + 7746880);              // 819200 B
  int* ehi     = (int*)(ws + 8566080);                   // ecap ints
  long long avail = ((long long)ws_size - 8566080ll) / 4ll;
  if (avail > 2000000ll) avail = 2000000ll;
  if (avail < 0ll) avail = 0ll;
  const int ecap = (int)avail;

  split_weights<<<800,256,0,stream>>>(w0,w1,w2,w3,wp);
  mlp_mfma<<<NBLK,512,0,stream>>>(pos,wp,b0,b1,b2,b3,wf,bf,sdf);

  TetArgs ta;
  ta.tet = tet; ta.pos = pos; ta.sdf = sdf;
  ta.codes = codes; ta.cnt = cnt; ta.ucnt = ucnt; ta.ucnt_ex = ucnt_ex;
  ta.ttot = ttot; ta.btot = btot; ta.btot_ex = btot_ex;
  ta.bseg = bseg; ta.bseg_ex = bseg_ex;
  ta.ubt = ubt; ta.ubt_ex = ubt_ex; ta.meta = meta; ta.tscan = tscan;
  ta.ehi = ehi; ta.ecap = ecap; ta.out = out; ta.out_size = out_size;
  void* kargs[] = { &ta };
  hipLaunchCooperativeKernel((const void*)coop_tets, dim3(CG), dim3(CT), kargs, 0, stream);
}

// Round 8
// 607.093 us; speedup vs baseline: 1.8506x; 1.8506x over previous
//
#include <hip/hip_runtime.h>
#include <cstdint>
#include <cstddef>

#define NV 200000
#define NT 800000
#define ROWS 64
#define NBLK 3125   // 3125*64 = 200000 exactly; also 3125*256 = 800000 exactly

typedef unsigned int u32;
typedef unsigned long long u64;
typedef unsigned short ushort_t;

typedef __attribute__((ext_vector_type(8))) _Float16 half8;
typedef __attribute__((ext_vector_type(4))) float f32x4;
#define MFMA16F __builtin_amdgcn_mfma_f32_16x16x32_f16

// ---------------- marching-tets tables ----------------
__constant__ int c_tri[16][6] = {
  {-1,-1,-1,-1,-1,-1},{1,0,2,-1,-1,-1},{4,0,3,-1,-1,-1},{1,4,2,1,3,4},
  {3,1,5,-1,-1,-1},{2,3,0,2,5,3},{1,4,0,1,5,4},{4,2,5,-1,-1,-1},
  {4,5,2,-1,-1,-1},{4,1,0,4,5,1},{3,2,0,3,5,2},{1,3,5,-1,-1,-1},
  {4,1,2,4,3,1},{3,0,4,-1,-1,-1},{2,0,1,-1,-1,-1},{-1,-1,-1,-1,-1,-1}};
__constant__ int c_ntri[16] = {0,1,1,2,1,2,2,1,1,2,2,1,2,1,1,0};
__constant__ int c_be[12] = {0,1,0,2,0,3,1,2,1,3,2,3};

// ---------------- fp16 Dekker 2-way split: x ~= h + m*2^-11 ----------------
__device__ __forceinline__ void split2(float x, _Float16& h, _Float16& m){
  h = (_Float16)x;
  const float r = x - (float)h;
  m = (_Float16)(r * 2048.0f);
}

// ---------------- weight split prep + workspace zeroing (fused memsets) ----------------
__global__ void split_weights(const float* __restrict__ w0, const float* __restrict__ w1,
                              const float* __restrict__ w2, const float* __restrict__ w3,
                              _Float16* __restrict__ wp,
                              u32* __restrict__ cnt_z, u32* __restrict__ cur_z)
{
  const int idx = blockIdx.x*256 + threadIdx.x;   // 0..204799
  if (idx < NV){ cnt_z[idx] = 0u; cur_z[idx] = 0u; }
  int base, k, n, psz;
  float val;
  if (idx < 8192){                                  // layer0: K=27 padded to 32
    base = 0; psz = 8192; k = idx >> 8; n = idx & 255;
    val = (k < 27) ? w0[k*256 + n] : 0.f;
  } else {
    int r = idx - 8192;
    const int l = r >> 16;                          // 0..2 -> layers 1..3
    r &= 65535;
    k = r >> 8; n = r & 255; psz = 65536;
    base = 16384 + l*131072;
    const float* w = (l==0) ? w1 : (l==1) ? w2 : w3;
    val = w[k*256 + n];
  }
  _Float16 h, m; split2(val, h, m);
  const int c = k >> 5, kk = k & 31;
  const int off = (c*256 + n)*32 + kk;
  wp[base + off] = h;
  wp[base + psz + off] = m;
}

// ---------------- MFMA MLP (unchanged from round 4: ~255 us, 2 blocks/CU) ----------------
template<int NC, bool LAST>
__device__ __forceinline__ void layer_run(
    const _Float16* __restrict__ Wl, const float* __restrict__ Bv,
    const float* __restrict__ wfv,
    _Float16 (*Af)[ROWS][264], float (*part)[8],
    int lane, int wv)
{
  const int l15 = lane & 15, q = lane >> 4;
  const int col0 = wv * 32;
  f32x4 g0[4][2], g1[4][2];
#pragma unroll
  for (int i=0;i<4;i++)
#pragma unroll
    for (int j=0;j<2;j++){ g0[i][j] = (f32x4){0.f,0.f,0.f,0.f}; g1[i][j] = (f32x4){0.f,0.f,0.f,0.f}; }

  const _Float16* bp = Wl + (u32)((col0 + l15)*32 + q*8);
  half8 bA[2][2], bB[2][2];

  auto loadB = [&](int c, half8 (*dst)[2]){
#pragma unroll
    for (int p=0;p<2;p++)
#pragma unroll
      for (int nt=0;nt<2;nt++)
        dst[p][nt] = *(const half8*)(bp + (p*NC + c)*8192 + nt*512);
  };
  auto compute = [&](int c, const half8 (*bb)[2]){
#pragma unroll
    for (int mt=0;mt<4;mt++){
      const _Float16* ap = &Af[0][mt*16 + l15][c*32 + q*8];
      const half8 ah = *(const half8*)(ap);
      const half8 am = *(const half8*)(ap + ROWS*264);
#pragma unroll
      for (int nt=0;nt<2;nt++){
        g0[mt][nt] = MFMA16F(ah, bb[0][nt], g0[mt][nt], 0,0,0);   // h*h
        g1[mt][nt] = MFMA16F(ah, bb[1][nt], g1[mt][nt], 0,0,0);   // h*m'
        g1[mt][nt] = MFMA16F(am, bb[0][nt], g1[mt][nt], 0,0,0);   // m'*h
      }
    }
  };

  loadB(0, bA);
  if (NC == 1){
    compute(0, bA);
  } else {
#pragma unroll 1
    for (int ch=0; ch<NC/2; ch++){
      const int c0 = 2*ch;
      loadB(c0+1, bB);
      compute(c0, bA);
      if (c0+2 < NC) loadB(c0+2, bA);
      compute(c0+1, bB);
    }
  }
  __syncthreads();

  const float S = 4.8828125e-4f;         // 2^-11
  if (!LAST){
#pragma unroll
    for (int nt=0;nt<2;nt++){
      const int col = col0 + nt*16 + l15;
      const float bias = Bv[col];
#pragma unroll
      for (int mt=0;mt<4;mt++)
#pragma unroll
        for (int reg=0;reg<4;reg++){
          const int row = mt*16 + q*4 + reg;
          const float v = fmaxf(g0[mt][nt][reg] + S*g1[mt][nt][reg] + bias, 0.f);
          _Float16 h,m; split2(v,h,m);
          Af[0][row][col] = h; Af[1][row][col] = m;
        }
    }
  } else {
    float pr[4][4];
#pragma unroll
    for (int mt=0;mt<4;mt++)
#pragma unroll
      for (int reg=0;reg<4;reg++) pr[mt][reg] = 0.f;
#pragma unroll
    for (int nt=0;nt<2;nt++){
      const int col = col0 + nt*16 + l15;
      const float bias = Bv[col];
      const float w = wfv[col];
#pragma unroll
      for (int mt=0;mt<4;mt++)
#pragma unroll
        for (int reg=0;reg<4;reg++)
          pr[mt][reg] += fmaxf(g0[mt][nt][reg] + S*g1[mt][nt][reg] + bias, 0.f) * w;
    }
#pragma unroll
    for (int s=1;s<16;s<<=1)
#pragma unroll
      for (int mt=0;mt<4;mt++)
#pragma unroll
        for (int reg=0;reg<4;reg++)
          pr[mt][reg] += __shfl_xor(pr[mt][reg], s, 64);
    if (l15 == 0){
#pragma unroll
      for (int mt=0;mt<4;mt++)
#pragma unroll
        for (int reg=0;reg<4;reg++)
          part[mt*16 + q*4 + reg][wv] = pr[mt][reg];
    }
  }
  __syncthreads();
}

__global__ __launch_bounds__(512,4) void mlp_mfma(
    const float* __restrict__ pos, const _Float16* __restrict__ wp,
    const float* __restrict__ b0, const float* __restrict__ b1,
    const float* __restrict__ b2, const float* __restrict__ b3,
    const float* __restrict__ wf, const float* __restrict__ bf,
    float* __restrict__ sdf)
{
  __shared__ _Float16 Af[2][ROWS][264];
  __shared__ float part[ROWS][8];
  const int tid = threadIdx.x;
  const int lane = tid & 63, wv = tid >> 6;
  const int row0 = blockIdx.x * ROWS;

#pragma unroll
  for (int it=0; it<4; it++){
    const int idx = it*512 + tid;
    const int r = idx & 63, f = idx >> 6;
    float val = 0.f;
    if (f < 3){
      val = pos[(row0 + r)*3 + f];
    } else if (f < 27){
      const int g = (f-3)/6, rem = (f-3)%6;
      const int d = rem % 3;
      const float x = pos[(row0 + r)*3 + d];
      const float fr = (float)(1 << g) * 3.14159265358979323846f;
      val = (rem < 3) ? sinf(fr*x) : cosf(fr*x);
    }
    _Float16 h,m; split2(val,h,m);
    Af[0][r][f] = h; Af[1][r][f] = m;
  }
  __syncthreads();

  layer_run<1,false>(wp + 0,      b0, nullptr, Af, part, lane, wv);
  layer_run<8,false>(wp + 16384,  b1, nullptr, Af, part, lane, wv);
  layer_run<8,false>(wp + 147456, b2, nullptr, Af, part, lane, wv);
  layer_run<8,true >(wp + 278528, b3, wf,      Af, part, lane, wv);

  if (tid < ROWS){
    float s = 0.f;
#pragma unroll
    for (int w=0; w<8; w++) s += part[tid][w];
    sdf[row0 + tid] = s + bf[0];
  }
}

// ---------------- scan helpers ----------------
__device__ __forceinline__ u32 bscan_u32(u32 v, u32* sh, int tid){
  sh[tid]=v; __syncthreads();
#pragma unroll
  for (int s=1;s<256;s<<=1){
    const u32 y = (tid>=s) ? sh[tid-s] : 0u;
    __syncthreads();
    sh[tid] += y;
    __syncthreads();
  }
  return sh[tid];
}
__device__ __forceinline__ u64 bscan_u64(u64 v, u64* sh, int tid){
  sh[tid]=v; __syncthreads();
#pragma unroll
  for (int s=1;s<256;s<<=1){
    const u64 y = (tid>=s) ? sh[tid-s] : 0ull;
    __syncthreads();
    sh[tid] += y;
    __syncthreads();
  }
  return sh[tid];
}

// ---------------- tet pass 1: codes, in-block stable (n1,n2) scan, bucket counts ----------------
// 3125 blocks x 256 threads x 1 tet (exact): tscan[t] = packed in-block exclusive (n1,n2)
__global__ void tet_count(const int* __restrict__ tet, const float* __restrict__ sdf,
    unsigned char* __restrict__ codes, u32* __restrict__ tscan, u32* __restrict__ tsum,
    u32* __restrict__ cnt)
{
  __shared__ u32 sh[256];
  const int tid = threadIdx.x;
  const int t = blockIdx.x*256 + tid;
  const int4 v = *(const int4*)(&tet[4*t]);
  const int o0 = sdf[v.x] > 0.f;
  const int o1 = sdf[v.y] > 0.f;
  const int o2 = sdf[v.z] > 0.f;
  const int o3 = sdf[v.w] > 0.f;
  const int code = o0 | (o1<<1) | (o2<<2) | (o3<<3);
  codes[t] = (unsigned char)code;
  const int nt = c_ntri[code];
  if (nt > 0){
    const int vv[4] = {v.x, v.y, v.z, v.w};
    const int oc[4] = {o0,o1,o2,o3};
#pragma unroll
    for (int e=0;e<6;e++){
      const int ia = c_be[2*e], ib = c_be[2*e+1];
      if (oc[ia] != oc[ib]){
        const int p = vv[ia], q = vv[ib];
        const int lo = p<q ? p : q;
        atomicAdd(&cnt[lo], 1u);
      }
    }
  }
  const u32 my = (u32)(nt==1) | ((u32)(nt==2)<<16);
  const u32 incl = bscan_u32(my, sh, tid);
  tscan[t] = incl - my;
  if (tid == 255) tsum[blockIdx.x] = incl;
}

// ---------------- mid-level scans (fused): blocks 0..195 cnt-segments; block 196 tsum scan ----------------
__global__ void scan_mid(const u32* __restrict__ cnt, u32* __restrict__ cntE,
                         u32* __restrict__ bsum, const u32* __restrict__ tsum,
                         u64* __restrict__ tsumE, u32* __restrict__ meta)
{
  __shared__ u32 sh[256];
  __shared__ u64 sh64[256];
  const int tid = threadIdx.x;
  if (blockIdx.x < 196){
    const int base = blockIdx.x*1024 + tid*4;
    u32 v[4]; u32 tot=0;
#pragma unroll
    for (int i=0;i<4;i++){
      const int idx = base+i;
      v[i] = (idx<NV) ? cnt[idx] : 0u;
      tot += v[i];
    }
    const u32 incl = bscan_u32(tot, sh, tid);
    u32 run = incl - tot;
#pragma unroll
    for (int i=0;i<4;i++){
      const int idx = base+i;
      if (idx<NV) cntE[idx] = run;
      run += v[i];
    }
    if (tid==255) bsum[blockIdx.x] = incl;
  } else {
    // scan tsum[3125] (packed u16 pairs) -> tsumE u64 exclusive (n1 lo32, n2 hi32)
    u64 loc[13]; u64 tot = 0ull;
#pragma unroll
    for (int i=0;i<13;i++){
      const int idx = tid*13 + i;
      const u32 p = (idx < NBLK) ? tsum[idx] : 0u;
      const u64 u = (u64)(p & 0xffffu) | ((u64)(p >> 16) << 32);
      loc[i] = u; tot += u;
    }
    const u64 incl = bscan_u64(tot, sh64, tid);
    u64 run = incl - tot;
#pragma unroll
    for (int i=0;i<13;i++){
      const int idx = tid*13 + i;
      if (idx < NBLK) tsumE[idx] = run;
      run += loc[i];
    }
    if (tid == 255){ meta[0] = (u32)(incl & 0xffffffffull); meta[1] = (u32)(incl >> 32); }
  }
}

// ---------------- top-level scan of a 196-entry array, in place -> exclusive ----------------
__global__ void scan_top(u32* __restrict__ arr, u32* __restrict__ meta, int slot)
{
  __shared__ u32 sh[256];
  const int tid = threadIdx.x;
  const u32 v = (tid < 196) ? arr[tid] : 0u;
  const u32 incl = bscan_u32(v, sh, tid);
  if (tid < 196) arr[tid] = incl - v;
  if (tid == 195) meta[slot] = incl;
}

// ---------------- fill pass ----------------
__global__ void fill_edges(const int* __restrict__ tet, const unsigned char* __restrict__ codes,
    const u32* __restrict__ cntE, const u32* __restrict__ bsum,
    u32* __restrict__ cur, int* __restrict__ ehi, int ecap)
{
  const int t = blockIdx.x*256 + threadIdx.x;
  const int code = codes[t];
  if (c_ntri[code] == 0) return;
  const int4 v = *(const int4*)(&tet[4*t]);
  const int vv[4]={v.x,v.y,v.z,v.w};
  const int oc[4]={code&1,(code>>1)&1,(code>>2)&1,(code>>3)&1};
#pragma unroll
  for (int e=0;e<6;e++){
    const int ia=c_be[2*e], ib=c_be[2*e+1];
    if (oc[ia]!=oc[ib]){
      const int p=vv[ia], q=vv[ib];
      const int lo = p<q?p:q, hi = p<q?q:p;
      const u32 off = bsum[lo>>10] + cntE[lo];
      const u32 slot = atomicAdd(&cur[lo],1u);
      const u32 idx = off + slot;
      if (idx < (u32)ecap) ehi[idx] = hi;
    }
  }
}

// ---------------- per-bucket sort + dedup ----------------
__global__ void sort_dedup(const u32* __restrict__ cnt, const u32* __restrict__ cntE,
    const u32* __restrict__ bsum, int* __restrict__ ehi, u32* __restrict__ ucnt, int ecap)
{
  const int lo = blockIdx.x*256 + threadIdx.x;
  if (lo >= NV) return;
  int n = (int)cnt[lo];
  const u32 off = bsum[lo>>10] + cntE[lo];
  long long rem = (long long)ecap - (long long)off;
  if (rem < 0) rem = 0;
  if ((long long)n > rem) n = (int)rem;
  int* b = ehi + off;
  for (int i=1;i<n;i++){
    const int key = b[i];
    int j=i-1;
    while (j>=0 && b[j] > key){ b[j+1]=b[j]; j--; }
    b[j+1]=key;
  }
  int u=0; int prev=-1;
  for (int i=0;i<n;i++){
    const int x = b[i];
    if (x != prev){ b[u]=x; u++; prev=x; }
  }
  ucnt[lo]=(u32)u;
}

// ---------------- mid-level scan of ucnt (196 segments of 1024) ----------------
__global__ void scan_mid2(const u32* __restrict__ ucnt, u32* __restrict__ ubaseE,
                          u32* __restrict__ usum)
{
  __shared__ u32 sh[256];
  const int tid = threadIdx.x;
  const int base = blockIdx.x*1024 + tid*4;
  u32 v[4]; u32 tot=0;
#pragma unroll
  for (int i=0;i<4;i++){
    const int idx = base+i;
    v[i] = (idx<NV) ? ucnt[idx] : 0u;
    tot += v[i];
  }
  const u32 incl = bscan_u32(tot, sh, tid);
  u32 run = incl - tot;
#pragma unroll
  for (int i=0;i<4;i++){
    const int idx = base+i;
    if (idx<NV) ubaseE[idx] = run;
    run += v[i];
  }
  if (tid==255) usum[blockIdx.x] = incl;
}

// ---------------- fused emit: blocks 0..781 verts; blocks 782..3906 faces ----------------
__global__ void emit_all(const int* __restrict__ tet, const float* __restrict__ pos,
    const float* __restrict__ sdf, const unsigned char* __restrict__ codes,
    const u32* __restrict__ tscan, const u64* __restrict__ tsumE, const u32* __restrict__ meta,
    const u32* __restrict__ ucnt, const u32* __restrict__ ubaseE, const u32* __restrict__ usum,
    const u32* __restrict__ cntE, const u32* __restrict__ bsum,
    const int* __restrict__ ehi, float* __restrict__ out, int out_size)
{
  const int tid = threadIdx.x;
  if (blockIdx.x < 782){
    const int lo = blockIdx.x*256 + tid;
    if (lo >= NV) return;
    const int u = (int)ucnt[lo];
    if (u == 0) return;
    const int* b = ehi + (bsum[lo>>10] + cntE[lo]);
    const u32 idbase = usum[lo>>10] + ubaseE[lo];
    const float s0 = sdf[lo];
    const float p0x = pos[3*lo], p0y = pos[3*lo+1], p0z = pos[3*lo+2];
    for (int j=0;j<u;j++){
      const int hi = b[j];
      const float s1 = sdf[hi];
      const float d = s0 - s1;
      const float vx = (p0x*(-s1) + pos[3*hi  ]*s0) / d;
      const float vy = (p0y*(-s1) + pos[3*hi+1]*s0) / d;
      const float vz = (p0z*(-s1) + pos[3*hi+2]*s0) / d;
      const long long w = 3ll*(long long)(idbase+(u32)j);
      if (w + 3 <= (long long)out_size){
        out[w]=vx; out[w+1]=vy; out[w+2]=vz;
      }
    }
  } else {
    const int t = (blockIdx.x - 782)*256 + tid;   // < 800000 exactly
    const int code = codes[t];
    const int nt = c_ntri[code];
    if (nt == 0) return;
    const u64 tb = tsumE[t>>8];
    const u32 ts = tscan[t];
    const u32 n1e = (u32)(tb & 0xffffffffull) + (ts & 0xffffu);
    const u32 n2e = (u32)(tb >> 32) + (ts >> 16);
    const u32 N1 = meta[0];
    const u32 M  = meta[3];
    const u32 fb = (nt==1) ? n1e : (N1 + 2u*n2e);
    const int4 v = *(const int4*)(&tet[4*t]);
    const int vv[4]={v.x,v.y,v.z,v.w};
    for (int r=0;r<nt;r++){
      for (int k=0;k<3;k++){
        const int e = c_tri[code][3*r+k];
        const int ia=c_be[2*e], ib=c_be[2*e+1];
        const int p=vv[ia], q=vv[ib];
        const int lo = p<q?p:q, hi = p<q?q:p;
        const int* b = ehi + (bsum[lo>>10] + cntE[lo]);
        const int u = (int)ucnt[lo];
        int id = -1;
        for (int j=0;j<u;j++){
          if (b[j]==hi){ id = (int)(usum[lo>>10] + ubaseE[lo]) + j; break; }
        }
        const long long w = 3ll*(long long)M + 3ll*(long long)(fb+(u32)r) + k;
        if (w < (long long)out_size && id >= 0) out[w] = (float)id;
      }
    }
  }
}

// ---------------- launch: 10 dispatches ----------------
extern "C" void kernel_launch(void* const* d_in, const int* in_sizes, int n_in,
                              void* d_out, int out_size, void* d_ws, size_t ws_size,
                              hipStream_t stream)
{
  (void)in_sizes; (void)n_in;
  const float* pos = (const float*)d_in[0];
  const int*   tet = (const int*)d_in[1];
  const float* w0 = (const float*)d_in[2];
  const float* b0 = (const float*)d_in[3];
  const float* w1 = (const float*)d_in[4];
  const float* b1 = (const float*)d_in[5];
  const float* w2 = (const float*)d_in[6];
  const float* b2 = (const float*)d_in[7];
  const float* w3 = (const float*)d_in[8];
  const float* b3 = (const float*)d_in[9];
  const float* wf = (const float*)d_in[10];
  const float* bf = (const float*)d_in[11];
  float* out = (float*)d_out;
  char* ws = (char*)d_ws;

  float*         sdf   = (float*)(ws + 0);               // 800000 B
  unsigned char* codes = (unsigned char*)(ws + 800000);  // 800000 B
  u32* cnt    = (u32*)(ws + 1600000);                    // 800000 B
  u32* cntE   = (u32*)(ws + 2400000);                    // 800000 B
  u32* ucnt   = (u32*)(ws + 3200000);                    // 800000 B
  u32* ubaseE = (u32*)(ws + 4000000);                    // 800000 B
  u32* cur    = (u32*)(ws + 4800000);                    // 800000 B
  u32* bsum   = (u32*)(ws + 5600000);                    // 1024 B (196 used)
  u32* usum   = (u32*)(ws + 5601024);                    // 1024 B
  u32* meta   = (u32*)(ws + 5602048);                    // 64 B
  u32* tsum   = (u32*)(ws + 5602112);                    // 12800 B (3125 used)
  u64* tsumE  = (u64*)(ws + 5614912);                    // 25088 B (3125 used)
  u32* tscan  = (u32*)(ws + 5640000);                    // 3200000 B
  _Float16* wp = (_Float16*)(ws + 8840000);              // 819200 B
  int* ehi    = (int*)(ws + 9659200);
  long long avail = ((long long)ws_size - 9659200ll) / 4ll;
  if (avail > 2000000ll) avail = 2000000ll;
  if (avail < 0ll) avail = 0ll;
  const int ecap = (int)avail;

  split_weights<<<800,256,0,stream>>>(w0,w1,w2,w3,wp,cnt,cur);
  mlp_mfma<<<NBLK,512,0,stream>>>(pos,wp,b0,b1,b2,b3,wf,bf,sdf);

  tet_count<<<NBLK,256,0,stream>>>(tet,sdf,codes,tscan,tsum,cnt);
  scan_mid<<<197,256,0,stream>>>(cnt,cntE,bsum,tsum,tsumE,meta);    // meta[0]=N1, meta[1]=N2
  scan_top<<<1,256,0,stream>>>(bsum,meta,2);                        // bsum -> exclusive
  fill_edges<<<NBLK,256,0,stream>>>(tet,codes,cntE,bsum,cur,ehi,ecap);
  sort_dedup<<<782,256,0,stream>>>(cnt,cntE,bsum,ehi,ucnt,ecap);
  scan_mid2<<<196,256,0,stream>>>(ucnt,ubaseE,usum);
  scan_top<<<1,256,0,stream>>>(usum,meta,3);                        // meta[3]=M
  emit_all<<<3907,256,0,stream>>>(tet,pos,sdf,codes,tscan,tsumE,meta,
                                  ucnt,ubaseE,usum,cntE,bsum,ehi,out,out_size);
}